// Round 6
// baseline (126.754 us; speedup 1.0000x reference)
//
#include <hip/hip_runtime.h>
#include <float.h>

#define N_SRC 20000
#define N_TAR 20000
#define TPB 256
#define T 8                       // targets per thread (named scalars, no arrays)
#define TGT_PER_BLK (TPB * T)     // 2048
#define TBLK 10                   // ceil(20000 / 2048)
#define SC 52                     // source chunks; TBLK*SC = 520 blocks ~ 2/CU
#define CHUNK 385                 // 52*385 = 20020 >= 20000
#define FBLOCKS ((N_TAR + TPB - 1) / TPB)   // 79

// Kernel 1: per (target-block bx, source-chunk c) partial min over the chunk.
// q = 0.5*||s||^2 - t.s  so that 0.5*d2 = 0.5*||t||^2 + q.
// The T-target register tile is written as NAMED SCALARS: rounds 2-4 showed
// the allocator refuses to promote indexed arrays here (VGPR_Count=28 with a
// 32-float tile -> accvgpr/scratch traffic, ~2.4x VALU inflation).
#define DECL(j) \
    const int ti##j = min(tbase + (j) * TPB, N_TAR - 1); \
    const float ntx##j = -tar[ti##j * 3 + 0]; \
    const float nty##j = -tar[ti##j * 3 + 1]; \
    const float ntz##j = -tar[ti##j * 3 + 2]; \
    float m##j = FLT_MAX;

#define STEP(j) \
    m##j = fminf(m##j, fmaf(ntx##j, p.x, fmaf(nty##j, p.y, fmaf(ntz##j, p.z, p.w))));

#define STORE(j) \
    { const int t = tbase + (j) * TPB; if (t < N_TAR) part[c * N_TAR + t] = m##j; }

__global__ __launch_bounds__(TPB) void nn_partial_min(
    const float* __restrict__ src, const float* __restrict__ tar,
    float* __restrict__ part, float* __restrict__ out)
{
    if (blockIdx.x == 0 && blockIdx.y == 0 && threadIdx.x == 0) out[0] = 0.f;

    __shared__ float4 sh[CHUNK];
    const int c = blockIdx.y;
    const int base = c * CHUNK;
    for (int i = threadIdx.x; i < CHUNK; i += TPB) {
        const int s = base + i;
        float x = 0.f, y = 0.f, z = 0.f, w = 3e38f;   // pad: never the min
        if (s < N_SRC) {
            x = src[s * 3 + 0];
            y = src[s * 3 + 1];
            z = src[s * 3 + 2];
            w = 0.5f * (x * x + y * y + z * z);
        }
        sh[i] = make_float4(x, y, z, w);
    }
    __syncthreads();

    const int tbase = blockIdx.x * TGT_PER_BLK + threadIdx.x;
    DECL(0) DECL(1) DECL(2) DECL(3) DECL(4) DECL(5) DECL(6) DECL(7)

#pragma unroll 2
    for (int i = 0; i < CHUNK; ++i) {
        const float4 p = sh[i];
        STEP(0) STEP(1) STEP(2) STEP(3) STEP(4) STEP(5) STEP(6) STEP(7)
    }

    STORE(0) STORE(1) STORE(2) STORE(3) STORE(4) STORE(5) STORE(6) STORE(7)
}

// Kernel 2: combine the SC chunk-mins per target, add 0.5*||t||^2,
// block-reduce, one atomicAdd per block into out[0] (zeroed by kernel 1).
__global__ __launch_bounds__(TPB) void nn_finalize(
    const float* __restrict__ tar, const float* __restrict__ part,
    float* __restrict__ out)
{
    const int t = blockIdx.x * TPB + threadIdx.x;
    float contrib = 0.f;
    if (t < N_TAR) {
        float m = FLT_MAX;
#pragma unroll
        for (int c = 0; c < SC; ++c) m = fminf(m, part[c * N_TAR + t]);
        const float tx = tar[t * 3 + 0];
        const float ty = tar[t * 3 + 1];
        const float tz = tar[t * 3 + 2];
        contrib = 0.5f * (tx * tx + ty * ty + tz * tz) + m;
    }
    for (int off = 32; off > 0; off >>= 1)
        contrib += __shfl_down(contrib, off);
    __shared__ float red[TPB / 64];
    if ((threadIdx.x & 63) == 0) red[threadIdx.x >> 6] = contrib;
    __syncthreads();
    if (threadIdx.x == 0) {
        float s = 0.f;
#pragma unroll
        for (int w = 0; w < TPB / 64; ++w) s += red[w];
        atomicAdd(out, s);
    }
}

extern "C" void kernel_launch(void* const* d_in, const int* in_sizes, int n_in,
                              void* d_out, int out_size, void* d_ws, size_t ws_size,
                              hipStream_t stream) {
    const float* src = (const float*)d_in[0];  // [20000,3] fp32
    const float* tar = (const float*)d_in[1];  // [20000,3] fp32
    float* out = (float*)d_out;                // scalar fp32
    float* part = (float*)d_ws;                // SC * N_TAR floats ~ 4.16 MB

    dim3 grid1(TBLK, SC);
    nn_partial_min<<<grid1, TPB, 0, stream>>>(src, tar, part, out);
    nn_finalize<<<FBLOCKS, TPB, 0, stream>>>(tar, part, out);
}

// Round 7
// 95.884 us; speedup vs baseline: 1.3219x; 1.3219x over previous
//
#include <hip/hip_runtime.h>
#include <float.h>

#define N_SRC 20000
#define N_TAR 20000
#define TPB 256
#define T 8                       // targets per thread
#define TGT_PER_BLK (TPB * T)     // 2048
#define TBLK 10                   // ceil(20000 / 2048)
#define SC 100                    // source chunks; TBLK*SC = 1000 blocks ~ 4/CU
#define CHUNK 200                 // 100*200 = 20000 exactly
#define FBLOCKS ((N_TAR + TPB - 1) / TPB)   // 79

// Kernel 1: per (target-block bx, source-chunk c) partial min over the chunk.
// q = 0.5*||s||^2 - t.s  so that 0.5*d2 = 0.5*||t||^2 + q.
//
// The inner step is INLINE ASM with "v" constraints: rounds 2-6 showed the
// allocator keeps the accumulator tile in AGPRs (VGPR_Count=28 < 32 live
// floats) and pays ~5 v_accvgpr moves per 4-op step (2.4x VALU inflation,
// 78 vs 33 instr/iter measured). "v" constraints force arch VGPRs at every
// use, making the AGPR strategy unprofitable.
#define DECL(j) \
    const int ti##j = min(tbase + (j) * TPB, N_TAR - 1); \
    const float ntx##j = -tar[ti##j * 3 + 0]; \
    const float nty##j = -tar[ti##j * 3 + 1]; \
    const float ntz##j = -tar[ti##j * 3 + 2]; \
    float m##j = FLT_MAX;

#define STEP(j) { float q; \
    asm("v_fma_f32 %0, %1, %2, %3" : "=v"(q) : "v"(ntz##j), "v"(p.z), "v"(p.w)); \
    asm("v_fma_f32 %0, %1, %2, %0" : "+v"(q) : "v"(nty##j), "v"(p.y)); \
    asm("v_fma_f32 %0, %1, %2, %0" : "+v"(q) : "v"(ntx##j), "v"(p.x)); \
    asm("v_min_f32 %0, %0, %1"     : "+v"(m##j) : "v"(q)); }

#define STORE(j) \
    { const int t = tbase + (j) * TPB; if (t < N_TAR) part[c * N_TAR + t] = m##j; }

__global__ __launch_bounds__(TPB) void nn_partial_min(
    const float* __restrict__ src, const float* __restrict__ tar,
    float* __restrict__ part, float* __restrict__ out)
{
    if (blockIdx.x == 0 && blockIdx.y == 0 && threadIdx.x == 0) out[0] = 0.f;

    __shared__ float4 sh[CHUNK];
    const int c = blockIdx.y;
    const int base = c * CHUNK;
    for (int i = threadIdx.x; i < CHUNK; i += TPB) {
        const int s = base + i;
        if (s < N_SRC) {
            const float x = src[s * 3 + 0];
            const float y = src[s * 3 + 1];
            const float z = src[s * 3 + 2];
            sh[i] = make_float4(x, y, z, 0.5f * (x * x + y * y + z * z));
        }
    }
    __syncthreads();

    const int tbase = blockIdx.x * TGT_PER_BLK + threadIdx.x;
    DECL(0) DECL(1) DECL(2) DECL(3) DECL(4) DECL(5) DECL(6) DECL(7)

#pragma unroll 2
    for (int i = 0; i < CHUNK; ++i) {
        const float4 p = sh[i];
        STEP(0) STEP(1) STEP(2) STEP(3) STEP(4) STEP(5) STEP(6) STEP(7)
    }

    STORE(0) STORE(1) STORE(2) STORE(3) STORE(4) STORE(5) STORE(6) STORE(7)
}

// Kernel 2: combine the SC chunk-mins per target, add 0.5*||t||^2,
// block-reduce, one atomicAdd per block into out[0] (zeroed by kernel 1).
__global__ __launch_bounds__(TPB) void nn_finalize(
    const float* __restrict__ tar, const float* __restrict__ part,
    float* __restrict__ out)
{
    const int t = blockIdx.x * TPB + threadIdx.x;
    float contrib = 0.f;
    if (t < N_TAR) {
        float m = FLT_MAX;
#pragma unroll
        for (int c = 0; c < SC; ++c) m = fminf(m, part[c * N_TAR + t]);
        const float tx = tar[t * 3 + 0];
        const float ty = tar[t * 3 + 1];
        const float tz = tar[t * 3 + 2];
        contrib = 0.5f * (tx * tx + ty * ty + tz * tz) + m;
    }
    for (int off = 32; off > 0; off >>= 1)
        contrib += __shfl_down(contrib, off);
    __shared__ float red[TPB / 64];
    if ((threadIdx.x & 63) == 0) red[threadIdx.x >> 6] = contrib;
    __syncthreads();
    if (threadIdx.x == 0) {
        float s = 0.f;
#pragma unroll
        for (int w = 0; w < TPB / 64; ++w) s += red[w];
        atomicAdd(out, s);
    }
}

extern "C" void kernel_launch(void* const* d_in, const int* in_sizes, int n_in,
                              void* d_out, int out_size, void* d_ws, size_t ws_size,
                              hipStream_t stream) {
    const float* src = (const float*)d_in[0];  // [20000,3] fp32
    const float* tar = (const float*)d_in[1];  // [20000,3] fp32
    float* out = (float*)d_out;                // scalar fp32
    float* part = (float*)d_ws;                // SC * N_TAR floats = 8 MB

    dim3 grid1(TBLK, SC);
    nn_partial_min<<<grid1, TPB, 0, stream>>>(src, tar, part, out);
    nn_finalize<<<FBLOCKS, TPB, 0, stream>>>(tar, part, out);
}